// Round 5
// baseline (263.266 us; speedup 1.0000x reference)
//
#include <hip/hip_runtime.h>
#include <hip/hip_bf16.h>

// VectorQuantizer: B=16, D=256, T=2048, K=1024, N=B*T=32768
// inputs: [B, D, T] fp32 ; embeddings: [K, D] fp32
// outputs (concat, fp32): quantized_st [B,D,T] | loss | e_latent | q_latent | indices [32768]
#define NB 16
#define ND 256
#define NT 2048
#define NK 1024
#define NN (NB * NT)
#define QSIZE (NB * ND * NT)
#define SCL_OFF QSIZE
#define IDX_OFF (QSIZE + 3)
// bf16-split score error ~3e-6 est / ~1e-5 worst; TAU=4e-5 -> ~2100 rows refined exactly.
#define TAU 4.0e-5f

// ws layout (bytes)
#define WS_CNT   8        // int
#define WS_E2F   1024     // float[1024]
#define WS_E2D   8192     // double[1024]
#define WS_IDX   16384    // int[32768]
#define WS_LIST  147456   // int[32768]
#define WS_BPACK 278528   // 1 MB: B-fragment-packed E, bf16 hi|lo
#define WS_ET    1327104  // 1 MB: float ET[256][1024] (E transposed, for coalesced refine)
#define WS_PART  2375680  // double[1024] per-block MSE partials

typedef __attribute__((ext_vector_type(8))) short bf16x8;
typedef __attribute__((ext_vector_type(4))) float f32x4;
#define MFMA16(a, b, c) __builtin_amdgcn_mfma_f32_16x16x32_bf16(a, b, c, 0, 0, 0)

__device__ inline void bf16split(float v, short& hi, short& lo) {
    union { __hip_bfloat16 b; short s; } uh, ul;
    uh.b = __float2bfloat16(v);
    float hf = __bfloat162float(uh.b);
    ul.b = __float2bfloat16(v - hf);
    hi = uh.s; lo = ul.s;
}

// ---------------- e2[k] (fp64 + fp32) + ET transpose + zero refine counter
__global__ __launch_bounds__(64) void vq_e2(const float4* __restrict__ E4,
                                            double* __restrict__ e2d,
                                            float* __restrict__ e2f,
                                            float* __restrict__ ET,
                                            int* __restrict__ cnt) {
    int k = blockIdx.x;
    int lane = threadIdx.x;
    float4 v = E4[k * 64 + lane];
    // ET[d][k] = E[k][d]
    ET[(size_t)(4 * lane + 0) * NK + k] = v.x;
    ET[(size_t)(4 * lane + 1) * NK + k] = v.y;
    ET[(size_t)(4 * lane + 2) * NK + k] = v.z;
    ET[(size_t)(4 * lane + 3) * NK + k] = v.w;
    double s = (double)v.x * v.x + (double)v.y * v.y + (double)v.z * v.z + (double)v.w * v.w;
    #pragma unroll
    for (int off = 32; off; off >>= 1) s += __shfl_down(s, off, 64);
    if (lane == 0) { e2d[k] = s; e2f[k] = (float)s; }
    if (k == 0 && lane == 0) cnt[0] = 0;
}

// ---------------- Pack E into MFMA B-fragment layout, bf16 hi/lo split.
// Bpack[cc][split][ds][lane][j]: code c = cc*16 + (lane&15), d = ds*32 + (lane>>4)*8 + j.
__global__ __launch_bounds__(64) void vq_prep_bpack(const float4* __restrict__ E4,
                                                    uint4* __restrict__ Bp4) {
    const int cc = blockIdx.x >> 3;
    const int ds = blockIdx.x & 7;
    const int lane = threadIdx.x;
    const int c = cc * 16 + (lane & 15);
    const int q = lane >> 4;
    float4 v0 = E4[(size_t)c * 64 + ds * 8 + q * 2];
    float4 v1 = E4[(size_t)c * 64 + ds * 8 + q * 2 + 1];
    float vals[8] = {v0.x, v0.y, v0.z, v0.w, v1.x, v1.y, v1.z, v1.w};
    union { short s[8]; uint4 v; } hi, lo;
    #pragma unroll
    for (int j = 0; j < 8; ++j) bf16split(vals[j], hi.s[j], lo.s[j]);
    Bp4[(size_t)cc * 1024 + ds * 64 + lane]       = hi.v;
    Bp4[(size_t)cc * 1024 + 512 + ds * 64 + lane] = lo.v;
}

// ---------------- Pass 1: MFMA bf16-split distance GEMM + per-row argmin (b1/b2 margin)
// 256 thr = 4 waves; wave = ONE 16-row tile; block = 64 rows; grid = 512 (2 blocks/CU).
// 3 independent MFMA chains/wave; double-buffered LDS, 1 barrier/chunk; 2 waves/SIMD
// so one block's barrier overlaps the co-resident block's MFMA stream.
__global__ __launch_bounds__(256, 2) void vq_pass1(const float* __restrict__ X,
                                                   const uint4* __restrict__ Bp4,
                                                   const float* __restrict__ e2f,
                                                   int* __restrict__ idx_ws,
                                                   int* __restrict__ cnt,
                                                   int* __restrict__ list,
                                                   float* __restrict__ out) {
    __shared__ uint4 Bl4[2][1024];   // 32 KB double buffer, chunk = 16 codes
    const int tid  = threadIdx.x;
    const int lane = tid & 63;
    const int w    = tid >> 6;
    const int n0   = blockIdx.x * 64;
    const int b    = n0 >> 11;
    const int t0   = n0 & (NT - 1);
    const int m16  = lane & 15;
    const int q    = lane >> 4;

    // A fragment: lane holds A[m=lane&15][k=q*8+j] for d = ds*32 + q*8 + j.
    bf16x8 ah[8], al[8];
    const float* Xb = X + (size_t)b * (ND * NT);
    {
        const int trow = t0 + w * 16 + m16;
        #pragma unroll
        for (int ds = 0; ds < 8; ++ds) {
            #pragma unroll
            for (int j = 0; j < 8; ++j) {
                const int d = ds * 32 + q * 8 + j;
                float v = Xb[(size_t)d * NT + trow];
                short h, l; bf16split(v, h, l);
                ah[ds][j] = h; al[ds][j] = l;
            }
        }
    }

    float b1[4], b2[4]; int i1[4];
    #pragma unroll
    for (int r = 0; r < 4; ++r) { b1[r] = 3e38f; b2[r] = 3e38f; i1[r] = 0; }

    uint4 pre[4];
    #pragma unroll
    for (int i = 0; i < 4; ++i) pre[i] = Bp4[tid + 256 * i];
    #pragma unroll
    for (int i = 0; i < 4; ++i) Bl4[0][tid + 256 * i] = pre[i];
    __syncthreads();

    for (int cc = 0; cc < 64; ++cc) {
        const bf16x8* Bf = (const bf16x8*)Bl4[cc & 1];
        if (cc < 63) {
            #pragma unroll
            for (int i = 0; i < 4; ++i) pre[i] = Bp4[(size_t)(cc + 1) * 1024 + tid + 256 * i];
        }
        f32x4 hh = {0.f,0.f,0.f,0.f}, lh = {0.f,0.f,0.f,0.f}, hl = {0.f,0.f,0.f,0.f};
        #pragma unroll
        for (int ds = 0; ds < 8; ++ds) {
            bf16x8 bh = Bf[ds * 64 + lane];
            bf16x8 bl = Bf[512 + ds * 64 + lane];
            hh = MFMA16(ah[ds], bh, hh);    // 3 independent chains
            lh = MFMA16(al[ds], bh, lh);
            hl = MFMA16(ah[ds], bl, hl);
        }
        if (cc < 63) {
            #pragma unroll
            for (int i = 0; i < 4; ++i) Bl4[(cc + 1) & 1][tid + 256 * i] = pre[i];
            __syncthreads();
        }
        const float e2v = e2f[cc * 16 + m16];
        const int  code = cc * 16 + m16;
        #pragma unroll
        for (int r = 0; r < 4; ++r) {
            float s0 = e2v - 2.0f * (hh[r] + lh[r] + hl[r]);
            if (s0 < b1[r]) { b2[r] = b1[r]; b1[r] = s0; i1[r] = code; }
            else if (s0 < b2[r]) b2[r] = s0;
        }
    }

    // Reduce across the 16 code-classes (lanes within each 16-group share rows).
    #pragma unroll
    for (int r = 0; r < 4; ++r) {
        float B1 = b1[r], B2 = b2[r]; int I1 = i1[r];
        #pragma unroll
        for (int mm = 1; mm < 16; mm <<= 1) {
            float o1 = __shfl_xor(B1, mm, 16);
            float o2 = __shfl_xor(B2, mm, 16);
            int   oi = __shfl_xor(I1, mm, 16);
            if (o1 < B1 || (o1 == B1 && oi < I1)) { B2 = fminf(B1, o2); B1 = o1; I1 = oi; }
            else B2 = fminf(B2, o1);
        }
        if (m16 == 0) {
            int n = n0 + w * 16 + q * 4 + r;   // C/D: row = quad*4 + reg
            idx_ws[n] = I1;
            out[IDX_OFF + n] = (float)I1;
            if (B2 - B1 < TAU) { int p = atomicAdd(cnt, 1); list[p] = n; }
        }
    }
}

// ---------------- Refine: exact fp64 argmin for flagged rows; 4 rows/pass share E reads.
// ET[d][k] layout: lane tid reads consecutive floats -> fully coalesced.
__global__ __launch_bounds__(256, 2) void vq_refine(const float* __restrict__ X,
                                                    const float* __restrict__ ET,
                                                    const double* __restrict__ e2d,
                                                    const int* __restrict__ cnt,
                                                    const int* __restrict__ list,
                                                    int* __restrict__ idx_ws,
                                                    float* __restrict__ out) {
    __shared__ double xs[4][256];
    __shared__ double sm_s[4][4];
    __shared__ int    sm_k[4][4];
    const int m = cnt[0];
    const int tid = threadIdx.x;
    for (int p = blockIdx.x; p * 4 < m; p += 512) {
        int nrow[4];
        #pragma unroll
        for (int g = 0; g < 4; ++g) {
            int j = p * 4 + g;
            nrow[g] = list[j < m ? j : m - 1];
        }
        #pragma unroll
        for (int g = 0; g < 4; ++g) {
            int n = nrow[g]; int bb = n >> 11; int tt = n & (NT - 1);
            xs[g][tid] = (double)X[((size_t)bb * ND + tid) * NT + tt];
        }
        __syncthreads();
        double acc[4][4];   // [kk][g]
        #pragma unroll
        for (int kk = 0; kk < 4; ++kk)
            #pragma unroll
            for (int g = 0; g < 4; ++g) acc[kk][g] = 0.0;
        #pragma unroll 2
        for (int dd = 0; dd < 256; ++dd) {
            float e0 = ET[(size_t)dd * NK +   0 + tid];   // coalesced dword loads
            float e1 = ET[(size_t)dd * NK + 256 + tid];
            float e2 = ET[(size_t)dd * NK + 512 + tid];
            float e3 = ET[(size_t)dd * NK + 768 + tid];
            #pragma unroll
            for (int g = 0; g < 4; ++g) {
                double xv = xs[g][dd];                    // LDS broadcast (free)
                acc[0][g] += xv * (double)e0;
                acc[1][g] += xv * (double)e1;
                acc[2][g] += xv * (double)e2;
                acc[3][g] += xv * (double)e3;
            }
        }
        #pragma unroll
        for (int g = 0; g < 4; ++g) {
            double bs = 1e300; int bk = 0x7fffffff;
            #pragma unroll
            for (int kk = 0; kk < 4; ++kk) {
                int k = kk * 256 + tid;
                double s = e2d[k] - 2.0 * acc[kk][g];
                if (s < bs) { bs = s; bk = k; }           // kk ascending: first-index wins
            }
            #pragma unroll
            for (int mm = 1; mm < 64; mm <<= 1) {
                double os = __shfl_xor(bs, mm, 64);
                int    ok = __shfl_xor(bk, mm, 64);
                if (os < bs || (os == bs && ok < bk)) { bs = os; bk = ok; }
            }
            if ((tid & 63) == 0) { sm_s[tid >> 6][g] = bs; sm_k[tid >> 6][g] = bk; }
        }
        __syncthreads();
        if (tid < 4) {
            double Bv = 1e300; int Kv = 0x7fffffff;
            for (int ww = 0; ww < 4; ++ww) {
                double s2 = sm_s[ww][tid]; int k2 = sm_k[ww][tid];
                if (s2 < Bv || (s2 == Bv && k2 < Kv)) { Bv = s2; Kv = k2; }
            }
            if (p * 4 + tid < m) {
                int n = nrow[tid];
                idx_ws[n] = Kv;
                out[IDX_OFF + n] = (float)Kv;
            }
        }
        __syncthreads();
    }
}

// ---------------- Gather via LDS tile-transpose + per-block MSE partial (no global atomics)
__global__ __launch_bounds__(256) void vq_gather(const float* __restrict__ X,
                                                 const float4* __restrict__ E4,
                                                 const int* __restrict__ idx_ws,
                                                 float* __restrict__ out,
                                                 double* __restrict__ part) {
    __shared__ float Eq[32 * 257];
    __shared__ double sm[4];
    const int bt = blockIdx.x;
    const int b  = bt >> 6;
    const int t0 = (bt & 63) << 5;
    const int* irow = idx_ws + b * NT + t0;
    {
        const int r  = threadIdx.x >> 3;
        const int l8 = threadIdx.x & 7;
        const int id = irow[r];
        const float4* er = E4 + (size_t)id * 64;
        #pragma unroll
        for (int it = 0; it < 8; ++it) {
            int c = l8 + (it << 3);
            float4 v = er[c];
            float* p = &Eq[r * 257 + 4 * c];
            p[0] = v.x; p[1] = v.y; p[2] = v.z; p[3] = v.w;
        }
    }
    __syncthreads();
    const int tw = threadIdx.x & 31;
    const int dg = threadIdx.x >> 5;
    double ls = 0.0;
    #pragma unroll 8
    for (int it = 0; it < 32; ++it) {
        const int d = dg + (it << 3);
        const float qv = Eq[tw * 257 + d];
        const size_t off = ((size_t)b * ND + d) * NT + t0 + tw;
        const float x = X[off];
        out[off] = x + (qv - x);             // straight-through, reference rounding
        const double df = (double)qv - (double)x;
        ls = fma(df, df, ls);
    }
    #pragma unroll
    for (int o = 32; o; o >>= 1) ls += __shfl_down(ls, o, 64);
    if ((threadIdx.x & 63) == 0) sm[threadIdx.x >> 6] = ls;
    __syncthreads();
    if (threadIdx.x == 0) part[bt] = sm[0] + sm[1] + sm[2] + sm[3];
}

// ---------------- Finalize: reduce 1024 partials, write scalars
__global__ __launch_bounds__(256) void vq_final(const double* __restrict__ part,
                                                float* __restrict__ out) {
    __shared__ double sm[4];
    const int tid = threadIdx.x;
    double s = part[tid] + part[tid + 256] + part[tid + 512] + part[tid + 768];
    #pragma unroll
    for (int o = 32; o; o >>= 1) s += __shfl_down(s, o, 64);
    if ((tid & 63) == 0) sm[tid >> 6] = s;
    __syncthreads();
    if (tid == 0) {
        double mse = (sm[0] + sm[1] + sm[2] + sm[3]) * (1.0 / (double)QSIZE);
        out[SCL_OFF + 0] = (float)(1.25 * mse);
        out[SCL_OFF + 1] = (float)mse;
        out[SCL_OFF + 2] = (float)mse;
    }
}

extern "C" void kernel_launch(void* const* d_in, const int* in_sizes, int n_in,
                              void* d_out, int out_size, void* d_ws, size_t ws_size,
                              hipStream_t stream) {
    const float* X = (const float*)d_in[0];   // [16, 256, 2048]
    const float* E = (const float*)d_in[1];   // [1024, 256]
    float* out = (float*)d_out;

    char* ws = (char*)d_ws;
    int*    cnt   = (int*)   (ws + WS_CNT);
    float*  e2f   = (float*) (ws + WS_E2F);
    double* e2d   = (double*)(ws + WS_E2D);
    int*    idxws = (int*)   (ws + WS_IDX);
    int*    list  = (int*)   (ws + WS_LIST);
    uint4*  bpack = (uint4*) (ws + WS_BPACK);
    float*  et    = (float*) (ws + WS_ET);
    double* part  = (double*)(ws + WS_PART);

    vq_e2        <<<NK, 64, 0, stream>>>((const float4*)E, e2d, e2f, et, cnt);
    vq_prep_bpack<<<512, 64, 0, stream>>>((const float4*)E, bpack);
    vq_pass1     <<<NN / 64, 256, 0, stream>>>(X, bpack, e2f, idxws, cnt, list, out);
    vq_refine    <<<512, 256, 0, stream>>>(X, et, e2d, cnt, list, idxws, out);
    vq_gather    <<<NB * (NT / 32), 256, 0, stream>>>(X, (const float4*)E, idxws, out, part);
    vq_final     <<<1, 256, 0, stream>>>(part, out);
}

// Round 6
// 216.163 us; speedup vs baseline: 1.2179x; 1.2179x over previous
//
#include <hip/hip_runtime.h>
#include <hip/hip_bf16.h>

// VectorQuantizer: B=16, D=256, T=2048, K=1024, N=B*T=32768
// inputs: [B, D, T] fp32 ; embeddings: [K, D] fp32
// outputs (concat, fp32): quantized_st [B,D,T] | loss | e_latent | q_latent | indices [32768]
#define NB 16
#define ND 256
#define NT 2048
#define NK 1024
#define NN (NB * NT)
#define QSIZE (NB * ND * NT)
#define SCL_OFF QSIZE
#define IDX_OFF (QSIZE + 3)
// bf16-split score error ~3e-6 est / ~1e-5 worst; TAU=4e-5 -> ~2000 rows refined exactly.
#define TAU 4.0e-5f

// ws layout (bytes) — base footprint 1.99 MB (proven safe); ET optional (+1 MB)
#define WS_CNT   0         // int
#define WS_PART  64        // double[1024]
#define WS_E2F   8448      // float[1024]
#define WS_E2D   12544     // double[1024]
#define WS_LIST  20736     // int[32768]
#define WS_B1S   151808    // float[2][32768] per-slice best
#define WS_B2S   413952    // float[2][32768] per-slice second-best
#define WS_I1S   676096    // int[2][32768] per-slice argmin
#define WS_BPACK 938240    // 1 MB: B-fragment-packed E, bf16 hi|lo
#define WS_ET    1986816   // 1 MB: float ET[256][1024] (optional, coalesced refine)
#define WS_NEED_ET (WS_ET + 1048576)

typedef __attribute__((ext_vector_type(8))) short bf16x8;
typedef __attribute__((ext_vector_type(4))) float f32x4;
#define MFMA16(a, b, c) __builtin_amdgcn_mfma_f32_16x16x32_bf16(a, b, c, 0, 0, 0)

__device__ inline void bf16split(float v, short& hi, short& lo) {
    union { __hip_bfloat16 b; short s; } uh, ul;
    uh.b = __float2bfloat16(v);
    float hf = __bfloat162float(uh.b);
    ul.b = __float2bfloat16(v - hf);
    hi = uh.s; lo = ul.s;
}

// ---------------- e2[k] (fp64 + fp32), optional ET transpose, zero refine counter
__global__ __launch_bounds__(64) void vq_e2(const float4* __restrict__ E4,
                                            double* __restrict__ e2d,
                                            float* __restrict__ e2f,
                                            float* __restrict__ ET, int use_et,
                                            int* __restrict__ cnt) {
    int k = blockIdx.x;
    int lane = threadIdx.x;
    float4 v = E4[k * 64 + lane];
    if (use_et) {
        ET[(size_t)(4 * lane + 0) * NK + k] = v.x;
        ET[(size_t)(4 * lane + 1) * NK + k] = v.y;
        ET[(size_t)(4 * lane + 2) * NK + k] = v.z;
        ET[(size_t)(4 * lane + 3) * NK + k] = v.w;
    }
    double s = (double)v.x * v.x + (double)v.y * v.y + (double)v.z * v.z + (double)v.w * v.w;
    #pragma unroll
    for (int off = 32; off; off >>= 1) s += __shfl_down(s, off, 64);
    if (lane == 0) { e2d[k] = s; e2f[k] = (float)s; }
    if (k == 0 && lane == 0) cnt[0] = 0;
}

// ---------------- Pack E into MFMA B-fragment layout, bf16 hi/lo split.
// Bpack[cc][split][ds][lane][j]: code c = cc*16 + (lane&15), d = ds*32 + (lane>>4)*8 + j.
__global__ __launch_bounds__(64) void vq_prep_bpack(const float4* __restrict__ E4,
                                                    uint4* __restrict__ Bp4) {
    const int cc = blockIdx.x >> 3;
    const int ds = blockIdx.x & 7;
    const int lane = threadIdx.x;
    const int c = cc * 16 + (lane & 15);
    const int q = lane >> 4;
    float4 v0 = E4[(size_t)c * 64 + ds * 8 + q * 2];
    float4 v1 = E4[(size_t)c * 64 + ds * 8 + q * 2 + 1];
    float vals[8] = {v0.x, v0.y, v0.z, v0.w, v1.x, v1.y, v1.z, v1.w};
    union { short s[8]; uint4 v; } hi, lo;
    #pragma unroll
    for (int j = 0; j < 8; ++j) bf16split(vals[j], hi.s[j], lo.s[j]);
    Bp4[(size_t)cc * 1024 + ds * 64 + lane]       = hi.v;
    Bp4[(size_t)cc * 1024 + 512 + ds * 64 + lane] = lo.v;
}

// ---------------- Pass 1: K-split MFMA bf16-split distance GEMM + per-slice argmin.
// grid 512: slice = bid&1 (512 codes), rows = (bid>>1)*128. 256 thr = 4 waves;
// wave = 2 row-tiles of 16 -> 6 independent MFMA chains (round-4 intensity);
// 2 blocks/CU -> 2 waves/SIMD so one block's barrier overlaps the other's MFMA.
__global__ __launch_bounds__(256, 2) void vq_pass1(const float* __restrict__ X,
                                                   const uint4* __restrict__ Bp4,
                                                   const float* __restrict__ e2f,
                                                   float* __restrict__ b1s,
                                                   float* __restrict__ b2s,
                                                   int* __restrict__ i1s) {
    __shared__ uint4 Bl4[2][1024];   // 32 KB double buffer, chunk = 16 codes
    const int tid   = threadIdx.x;
    const int lane  = tid & 63;
    const int w     = tid >> 6;
    const int slice = blockIdx.x & 1;
    const int n0    = (blockIdx.x >> 1) * 128;
    const int b     = n0 >> 11;
    const int t0    = n0 & (NT - 1);
    const int m16   = lane & 15;
    const int q     = lane >> 4;
    const uint4* Bps = Bp4 + (size_t)slice * 32768;   // 32 chunks x 1024 uint4

    // A fragments: lane holds A[m=lane&15][k=q*8+j] for d = ds*32 + q*8 + j.
    bf16x8 ah[2][8], al[2][8];
    const float* Xb = X + (size_t)b * (ND * NT);
    #pragma unroll
    for (int t = 0; t < 2; ++t) {
        const int trow = t0 + w * 32 + t * 16 + m16;
        #pragma unroll
        for (int ds = 0; ds < 8; ++ds) {
            #pragma unroll
            for (int j = 0; j < 8; ++j) {
                const int d = ds * 32 + q * 8 + j;
                float v = Xb[(size_t)d * NT + trow];
                short h, l; bf16split(v, h, l);
                ah[t][ds][j] = h; al[t][ds][j] = l;
            }
        }
    }

    float b1[2][4], b2[2][4]; int i1[2][4];
    #pragma unroll
    for (int t = 0; t < 2; ++t)
        #pragma unroll
        for (int r = 0; r < 4; ++r) { b1[t][r] = 3e38f; b2[t][r] = 3e38f; i1[t][r] = 0; }

    uint4 pre[4];
    #pragma unroll
    for (int i = 0; i < 4; ++i) pre[i] = Bps[tid + 256 * i];
    #pragma unroll
    for (int i = 0; i < 4; ++i) Bl4[0][tid + 256 * i] = pre[i];
    __syncthreads();

    for (int cc = 0; cc < 32; ++cc) {
        const bf16x8* Bf = (const bf16x8*)Bl4[cc & 1];
        if (cc < 31) {
            #pragma unroll
            for (int i = 0; i < 4; ++i) pre[i] = Bps[(size_t)(cc + 1) * 1024 + tid + 256 * i];
        }
        f32x4 hh0 = {0.f,0.f,0.f,0.f}, lh0 = {0.f,0.f,0.f,0.f}, hl0 = {0.f,0.f,0.f,0.f};
        f32x4 hh1 = {0.f,0.f,0.f,0.f}, lh1 = {0.f,0.f,0.f,0.f}, hl1 = {0.f,0.f,0.f,0.f};
        #pragma unroll
        for (int ds = 0; ds < 8; ++ds) {
            bf16x8 bh = Bf[ds * 64 + lane];
            bf16x8 bl = Bf[512 + ds * 64 + lane];
            hh0 = MFMA16(ah[0][ds], bh, hh0);   // 6 independent chains
            hh1 = MFMA16(ah[1][ds], bh, hh1);
            lh0 = MFMA16(al[0][ds], bh, lh0);
            lh1 = MFMA16(al[1][ds], bh, lh1);
            hl0 = MFMA16(ah[0][ds], bl, hl0);
            hl1 = MFMA16(ah[1][ds], bl, hl1);
        }
        if (cc < 31) {
            #pragma unroll
            for (int i = 0; i < 4; ++i) Bl4[(cc + 1) & 1][tid + 256 * i] = pre[i];
            __syncthreads();
        }
        const int  code = slice * 512 + cc * 16 + m16;
        const float e2v = e2f[code];
        #pragma unroll
        for (int r = 0; r < 4; ++r) {
            float s0 = e2v - 2.0f * (hh0[r] + lh0[r] + hl0[r]);
            if (s0 < b1[0][r]) { b2[0][r] = b1[0][r]; b1[0][r] = s0; i1[0][r] = code; }
            else if (s0 < b2[0][r]) b2[0][r] = s0;
            float s1 = e2v - 2.0f * (hh1[r] + lh1[r] + hl1[r]);
            if (s1 < b1[1][r]) { b2[1][r] = b1[1][r]; b1[1][r] = s1; i1[1][r] = code; }
            else if (s1 < b2[1][r]) b2[1][r] = s1;
        }
    }

    // Reduce across the 16 code-classes; write per-slice candidates.
    #pragma unroll
    for (int t = 0; t < 2; ++t) {
        #pragma unroll
        for (int r = 0; r < 4; ++r) {
            float B1 = b1[t][r], B2 = b2[t][r]; int I1 = i1[t][r];
            #pragma unroll
            for (int mm = 1; mm < 16; mm <<= 1) {
                float o1 = __shfl_xor(B1, mm, 16);
                float o2 = __shfl_xor(B2, mm, 16);
                int   oi = __shfl_xor(I1, mm, 16);
                if (o1 < B1 || (o1 == B1 && oi < I1)) { B2 = fminf(B1, o2); B1 = o1; I1 = oi; }
                else B2 = fminf(B2, o1);
            }
            if (m16 == 0) {
                int n = n0 + w * 32 + t * 16 + q * 4 + r;   // C/D: row = quad*4 + reg
                int s = slice * NN + n;
                b1s[s] = B1; b2s[s] = B2; i1s[s] = I1;
            }
        }
    }
}

// ---------------- Merge the two K-slices: final argmin + TAU flagging
__global__ __launch_bounds__(256) void vq_merge(const float* __restrict__ b1s,
                                                const float* __restrict__ b2s,
                                                const int* __restrict__ i1s,
                                                int* __restrict__ cnt,
                                                int* __restrict__ list,
                                                float* __restrict__ out) {
    const int n = blockIdx.x * 256 + threadIdx.x;
    float a1 = b1s[n],      a2 = b2s[n];      int ai = i1s[n];
    float c1 = b1s[NN + n], c2 = b2s[NN + n]; int ci = i1s[NN + n];
    float B1, B2; int I1;
    if (c1 < a1) { B1 = c1; I1 = ci; B2 = fminf(a1, c2); }   // tie -> slice0 (lower index) wins
    else         { B1 = a1; I1 = ai; B2 = fminf(a2, c1); }
    out[IDX_OFF + n] = (float)I1;
    if (B2 - B1 < TAU) { int p = atomicAdd(cnt, 1); list[p] = n; }
}

// ---------------- Refine: exact fp64 argmin for flagged rows; 4 rows/pass share E reads.
// use_et=1: coalesced ET[d][k] path; else float4 E rows (uncoalesced fallback).
__global__ __launch_bounds__(256, 2) void vq_refine(const float* __restrict__ X,
                                                    const float4* __restrict__ E4,
                                                    const float* __restrict__ ET, int use_et,
                                                    const double* __restrict__ e2d,
                                                    const int* __restrict__ cnt,
                                                    const int* __restrict__ list,
                                                    float* __restrict__ out) {
    __shared__ double xs[4][256];
    __shared__ double sm_s[4][4];
    __shared__ int    sm_k[4][4];
    const int m = cnt[0];
    const int tid = threadIdx.x;
    for (int p = blockIdx.x; p * 4 < m; p += 512) {
        int nrow[4];
        #pragma unroll
        for (int g = 0; g < 4; ++g) {
            int j = p * 4 + g;
            nrow[g] = list[j < m ? j : m - 1];
        }
        #pragma unroll
        for (int g = 0; g < 4; ++g) {
            int n = nrow[g]; int bb = n >> 11; int tt = n & (NT - 1);
            xs[g][tid] = (double)X[((size_t)bb * ND + tid) * NT + tt];
        }
        __syncthreads();
        double acc[4][4];   // [kk][g]
        #pragma unroll
        for (int kk = 0; kk < 4; ++kk)
            #pragma unroll
            for (int g = 0; g < 4; ++g) acc[kk][g] = 0.0;
        if (use_et) {
            #pragma unroll 2
            for (int dd = 0; dd < 256; ++dd) {
                float e0 = ET[(size_t)dd * NK +   0 + tid];
                float e1 = ET[(size_t)dd * NK + 256 + tid];
                float e2 = ET[(size_t)dd * NK + 512 + tid];
                float e3 = ET[(size_t)dd * NK + 768 + tid];
                #pragma unroll
                for (int g = 0; g < 4; ++g) {
                    double xv = xs[g][dd];
                    acc[0][g] += xv * (double)e0;
                    acc[1][g] += xv * (double)e1;
                    acc[2][g] += xv * (double)e2;
                    acc[3][g] += xv * (double)e3;
                }
            }
        } else {
            for (int dq = 0; dq < 64; ++dq) {
                #pragma unroll
                for (int kk = 0; kk < 4; ++kk) {
                    float4 ev = E4[(size_t)(kk * 256 + tid) * 64 + dq];
                    #pragma unroll
                    for (int g = 0; g < 4; ++g)
                        acc[kk][g] += xs[g][dq*4+0] * (double)ev.x + xs[g][dq*4+1] * (double)ev.y
                                    + xs[g][dq*4+2] * (double)ev.z + xs[g][dq*4+3] * (double)ev.w;
                }
            }
        }
        #pragma unroll
        for (int g = 0; g < 4; ++g) {
            double bs = 1e300; int bk = 0x7fffffff;
            #pragma unroll
            for (int kk = 0; kk < 4; ++kk) {
                int k = kk * 256 + tid;
                double s = e2d[k] - 2.0 * acc[kk][g];
                if (s < bs) { bs = s; bk = k; }
            }
            #pragma unroll
            for (int mm = 1; mm < 64; mm <<= 1) {
                double os = __shfl_xor(bs, mm, 64);
                int    ok = __shfl_xor(bk, mm, 64);
                if (os < bs || (os == bs && ok < bk)) { bs = os; bk = ok; }
            }
            if ((tid & 63) == 0) { sm_s[tid >> 6][g] = bs; sm_k[tid >> 6][g] = bk; }
        }
        __syncthreads();
        if (tid < 4) {
            double Bv = 1e300; int Kv = 0x7fffffff;
            for (int ww = 0; ww < 4; ++ww) {
                double s2 = sm_s[ww][tid]; int k2 = sm_k[ww][tid];
                if (s2 < Bv || (s2 == Bv && k2 < Kv)) { Bv = s2; Kv = k2; }
            }
            if (p * 4 + tid < m) out[IDX_OFF + nrow[tid]] = (float)Kv;
        }
        __syncthreads();
    }
}

// ---------------- Gather via LDS tile-transpose + per-block MSE partial
__global__ __launch_bounds__(256) void vq_gather(const float* __restrict__ X,
                                                 const float4* __restrict__ E4,
                                                 float* __restrict__ out,
                                                 double* __restrict__ part) {
    __shared__ float Eq[32 * 257];
    __shared__ double sm[4];
    const int bt = blockIdx.x;
    const int b  = bt >> 6;
    const int t0 = (bt & 63) << 5;
    const float* irowf = out + IDX_OFF + b * NT + t0;   // float-encoded indices (exact <=1024)
    {
        const int r  = threadIdx.x >> 3;
        const int l8 = threadIdx.x & 7;
        const int id = (int)irowf[r];
        const float4* er = E4 + (size_t)id * 64;
        #pragma unroll
        for (int it = 0; it < 8; ++it) {
            int c = l8 + (it << 3);
            float4 v = er[c];
            float* p = &Eq[r * 257 + 4 * c];
            p[0] = v.x; p[1] = v.y; p[2] = v.z; p[3] = v.w;
        }
    }
    __syncthreads();
    const int tw = threadIdx.x & 31;
    const int dg = threadIdx.x >> 5;
    double ls = 0.0;
    #pragma unroll 8
    for (int it = 0; it < 32; ++it) {
        const int d = dg + (it << 3);
        const float qv = Eq[tw * 257 + d];
        const size_t off = ((size_t)b * ND + d) * NT + t0 + tw;
        const float x = X[off];
        out[off] = x + (qv - x);             // straight-through, reference rounding
        const double df = (double)qv - (double)x;
        ls = fma(df, df, ls);
    }
    #pragma unroll
    for (int o = 32; o; o >>= 1) ls += __shfl_down(ls, o, 64);
    if ((threadIdx.x & 63) == 0) sm[threadIdx.x >> 6] = ls;
    __syncthreads();
    if (threadIdx.x == 0) part[bt] = sm[0] + sm[1] + sm[2] + sm[3];
}

// ---------------- Finalize: reduce 1024 partials, write scalars
__global__ __launch_bounds__(256) void vq_final(const double* __restrict__ part,
                                                float* __restrict__ out) {
    __shared__ double sm[4];
    const int tid = threadIdx.x;
    double s = part[tid] + part[tid + 256] + part[tid + 512] + part[tid + 768];
    #pragma unroll
    for (int o = 32; o; o >>= 1) s += __shfl_down(s, o, 64);
    if ((tid & 63) == 0) sm[tid >> 6] = s;
    __syncthreads();
    if (tid == 0) {
        double mse = (sm[0] + sm[1] + sm[2] + sm[3]) * (1.0 / (double)QSIZE);
        out[SCL_OFF + 0] = (float)(1.25 * mse);
        out[SCL_OFF + 1] = (float)mse;
        out[SCL_OFF + 2] = (float)mse;
    }
}

extern "C" void kernel_launch(void* const* d_in, const int* in_sizes, int n_in,
                              void* d_out, int out_size, void* d_ws, size_t ws_size,
                              hipStream_t stream) {
    const float* X = (const float*)d_in[0];   // [16, 256, 2048]
    const float* E = (const float*)d_in[1];   // [1024, 256]
    float* out = (float*)d_out;

    char* ws = (char*)d_ws;
    int*    cnt   = (int*)   (ws + WS_CNT);
    double* part  = (double*)(ws + WS_PART);
    float*  e2f   = (float*) (ws + WS_E2F);
    double* e2d   = (double*)(ws + WS_E2D);
    int*    list  = (int*)   (ws + WS_LIST);
    float*  b1s   = (float*) (ws + WS_B1S);
    float*  b2s   = (float*) (ws + WS_B2S);
    int*    i1s   = (int*)   (ws + WS_I1S);
    uint4*  bpack = (uint4*) (ws + WS_BPACK);
    float*  et    = (float*) (ws + WS_ET);
    const int use_et = (ws_size >= (size_t)WS_NEED_ET) ? 1 : 0;

    vq_e2        <<<NK, 64, 0, stream>>>((const float4*)E, e2d, e2f, et, use_et, cnt);
    vq_prep_bpack<<<512, 64, 0, stream>>>((const float4*)E, bpack);
    vq_pass1     <<<NN / 64, 256, 0, stream>>>(X, bpack, e2f, b1s, b2s, i1s);
    vq_merge     <<<NN / 256, 256, 0, stream>>>(b1s, b2s, i1s, cnt, list, out);
    vq_refine    <<<512, 256, 0, stream>>>(X, (const float4*)E, et, use_et, e2d, cnt, list, out);
    vq_gather    <<<NB * (NT / 32), 256, 0, stream>>>(X, (const float4*)E, out, part);
    vq_final     <<<1, 256, 0, stream>>>(part, out);
}